// Round 1
// baseline (309.689 us; speedup 1.0000x reference)
//
#include <hip/hip_runtime.h>
#include <cstdint>
#include <cstddef>

// SOM BMU: dists[b,m] = ||x[b] - W[:,m] + eps||, argmin/min over m.
//   sq = rowTerm[b] + colTerm[m] - 2*dot(x[b],W[:,m]) + D*eps^2
// dot via split-precision f16 MFMA (xh.wh + xh.wl + xl.wh, ~2^-22 rel err).
// R8: 128x256 block tile (96 MFMA/wave/iter -> barrier drain amortized 8x),
// GLDS staging with PRE-SWIZZLED storage format written by the prep pass:
//   addr16(r,c) = (r>>4)*32768 + (c>>2)*1024 + (c&3)*256 + (r&15)*16
// R9 (this round):
//   - prep W-path rewritten barrier-free: no LDS tile transpose; each thread
//     owns one column m (wave = 64 consecutive m -> coalesced 256B/instr),
//     4 waves split D into quarters, colTerm via one cpart[4][64] reduce.
//     x-path: one row per half-wave, shfl reduce, no barriers/LDS.
//     (old version: 2 barriers + LDS atomics per 1/16th of work -> ~110us,
//      latency-bound at 1.3 TB/s; traffic roofline is ~30us)
//   - som_mfma XCD-aware swizzle: all 16 row-blocks sharing a W col-slab land
//     on ONE XCD (slab=(g&7)+8*(g>>7)) -> W fetched ~once per slab instead of
//     ~4x (FETCH 277MB -> ~150MB predicted).
// Argmin via packed u64 key (dist_bits<<32 | m) + atomicMin.

#define B_  2048
#define D_  1024
#define M_  16384
#define EPS_ 1e-6f

typedef _Float16 v8h __attribute__((ext_vector_type(8)));
typedef float    v4f __attribute__((ext_vector_type(4)));

static __device__ __forceinline__ unsigned long long umin64(unsigned long long a,
                                                            unsigned long long b) {
    return a < b ? a : b;
}

// swizzled 16B-chunk address: row r, k-chunk c (8 f16 per chunk)
static __device__ __forceinline__ size_t addr16(int r, int c) {
    return (size_t)(r >> 4) * 32768 + (size_t)(c >> 2) * 1024 +
           (size_t)(c & 3) * 256 + (size_t)(r & 15) * 16;
}

#define GLDS16(g, l)                                                            \
    __builtin_amdgcn_global_load_lds(                                           \
        (const __attribute__((address_space(1))) void*)(g),                     \
        (__attribute__((address_space(3))) void*)(l), 16, 0, 0)

// ---------- fused prep: x->xh/xl + rowTerm, W->wth/wtl + colTerm, inits ----
// blocks 0..255: W cols (64 each, full D, one col per thread, no barriers in
// the hot loop). blocks 256..319: x rows (32 each, one row per half-wave).
// block 320: keys + loss-slot init.
__global__ __launch_bounds__(256) void prep(
    const float* __restrict__ x, const float* __restrict__ W,
    _Float16* __restrict__ xh, _Float16* __restrict__ xl,
    _Float16* __restrict__ wth, _Float16* __restrict__ wtl,
    float* __restrict__ rowTerm, float* __restrict__ colTerm,
    unsigned long long* __restrict__ keys, float* __restrict__ out)
{
    const int t = threadIdx.x;
    const int blk = blockIdx.x;
    if (blk < 256) {
        // one column m per thread; wave wq covers d-quarter [wq*256, wq*256+256)
        __shared__ float cpart[4][64];
        const int m_local = t & 63;
        const int wq = t >> 6;
        const int m = blk * 64 + m_local;
        const float* wp = W + m;
        const int cbase = wq * 32;      // 32 k-chunks of 8 per wave
        float part = 0.f;
        #pragma unroll 4
        for (int cl = 0; cl < 32; ++cl) {
            const int c = cbase + cl;
            const int d0 = c * 8;
            float vv[8];
            #pragma unroll
            for (int e = 0; e < 8; ++e)
                vv[e] = wp[(size_t)(d0 + e) * M_];   // wave = 256B coalesced
            v8h h, l;
            #pragma unroll
            for (int e = 0; e < 8; ++e) {
                _Float16 hi = (_Float16)vv[e];
                h[e] = hi; l[e] = (_Float16)(vv[e] - (float)hi);
                part += vv[e] * vv[e] - 2.0f * EPS_ * vv[e];
            }
            const size_t a = addr16(m, c);
            *(v8h*)((char*)wth + a) = h;
            *(v8h*)((char*)wtl + a) = l;
        }
        cpart[wq][m_local] = part;
        __syncthreads();
        if (t < 64)
            colTerm[blk * 64 + t] =
                cpart[0][t] + cpart[1][t] + cpart[2][t] + cpart[3][t];
    } else if (blk < 320) {
        // 32 rows per block; per pass: 8 rows, one row per half-wave
        const int rb0 = (blk - 256) * 32;
        const int w = t >> 6, L = t & 63;
        const int hl = L & 31;
        #pragma unroll
        for (int p = 0; p < 4; ++p) {
            const int r = rb0 + 8 * p + 2 * w + (L >> 5);
            const float* xr = x + (size_t)r * D_;
            float part = 0.f;
            #pragma unroll
            for (int i = 0; i < 4; ++i) {
                const int c = 32 * i + hl;           // half-wave = 1KB coalesced
                float4 q1 = *(const float4*)(xr + 8 * c);
                float4 q2 = *(const float4*)(xr + 8 * c + 4);
                float vv[8] = {q1.x, q1.y, q1.z, q1.w, q2.x, q2.y, q2.z, q2.w};
                v8h h, l;
                #pragma unroll
                for (int e = 0; e < 8; ++e) {
                    _Float16 hi = (_Float16)vv[e];
                    h[e] = hi; l[e] = (_Float16)(vv[e] - (float)hi);
                    part += vv[e] * vv[e] + 2.0f * EPS_ * vv[e];
                }
                const size_t a = addr16(r, c);
                *(v8h*)((char*)xh + a) = h;
                *(v8h*)((char*)xl + a) = l;
            }
            #pragma unroll
            for (int msk = 1; msk <= 16; msk <<= 1)
                part += __shfl_xor(part, msk, 64);   // stays within 32-lane half
            if (hl == 0) rowTerm[r] = part;
        }
    } else {
        for (int i = t; i < B_; i += 256) keys[i] = ~0ull;
        if (t == 0) out[3 * B_] = 0.f;
    }
}

// ---------- main MFMA distance GEMM + argmin ----------
// 128x256 block tile, 4 waves (2x2, each 64 rows x 128 cols), BK=32.
__global__ __launch_bounds__(256, 2) void som_mfma(
    const _Float16* __restrict__ xh, const _Float16* __restrict__ xl,
    const _Float16* __restrict__ wth, const _Float16* __restrict__ wtl,
    const float* __restrict__ rowTerm, const float* __restrict__ colTerm,
    unsigned long long* __restrict__ keys)
{
    __shared__ __align__(16) char smem[49152];   // Ah 8K | Al 8K | Bh 16K | Bl 16K
    _Float16* Ah = (_Float16*)smem;
    _Float16* Al = (_Float16*)(smem + 8192);
    _Float16* Bh = (_Float16*)(smem + 16384);
    _Float16* Bl = (_Float16*)(smem + 32768);

    const int t = threadIdx.x;
    const int g = blockIdx.x;
    // XCD-aware: round-robin dispatch puts g on XCD g&7; all 16 row-blocks of
    // a slab share g&7 -> same XCD L2 -> W slab fetched once per XCD.
    // bijective: g = (slab&7) + 8*row + 128*(slab>>3)
    const int slab = (g & 7) + 8 * (g >> 7);
    const int cb = slab * 256;
    const int rb = ((g >> 3) & 15) * 128;
    const int L = t & 63, w = t >> 6;
    const int wro = (w >> 1) * 64;
    const int wco = (w & 1) * 128;
    const int c16 = L & 15, kq = L >> 4;

    // staging: per call, wave wgrp covers one 16-row group (1 KB linear)
    const int wgrp = t >> 6;
    const int lane16 = (t & 63) * 16;
    const int ldsw = wgrp * 1024;                 // wave-uniform LDS base
    const size_t abase0 = (size_t)((rb >> 4) + wgrp) * 32768 + lane16;
    const size_t abase1 = abase0 + 4ull * 32768;
    const size_t bbase0 = (size_t)((cb >> 4) + wgrp) * 32768 + lane16;
    const size_t bbase1 = bbase0 + 4ull * 32768;
    const size_t bbase2 = bbase0 + 8ull * 32768;
    const size_t bbase3 = bbase0 + 12ull * 32768;

    const char* pxh = (const char*)xh;
    const char* pxl = (const char*)xl;
    const char* pwh = (const char*)wth;
    const char* pwl = (const char*)wtl;

    v4f acc[4][8];
    #pragma unroll
    for (int i = 0; i < 4; ++i)
        #pragma unroll
        for (int j = 0; j < 8; ++j) acc[i][j] = (v4f){0.f, 0.f, 0.f, 0.f};

    // fragment read offsets (f16 units): group grp -> grp*512 + lofs
    // lofs: chunk (L>>4)*128 + row (L&15)*8 -> 16-lane groups on 16
    // consecutive slots (conflict-free)
    const int lofs = kq * 128 + c16 * 8;
    int ia[4], ibx[8];
    #pragma unroll
    for (int i = 0; i < 4; ++i) ia[i] = ((wro >> 4) + i) * 512 + lofs;
    #pragma unroll
    for (int j = 0; j < 8; ++j) ibx[j] = ((wco >> 4) + j) * 512 + lofs;

    for (int S = 0; S < 32; ++S) {
        const size_t ko = (size_t)S * 1024;
        __syncthreads();
        GLDS16(pxh + abase0 + ko, smem + ldsw);
        GLDS16(pxh + abase1 + ko, smem + 4096 + ldsw);
        GLDS16(pxl + abase0 + ko, smem + 8192 + ldsw);
        GLDS16(pxl + abase1 + ko, smem + 12288 + ldsw);
        GLDS16(pwh + bbase0 + ko, smem + 16384 + ldsw);
        GLDS16(pwh + bbase1 + ko, smem + 20480 + ldsw);
        GLDS16(pwh + bbase2 + ko, smem + 24576 + ldsw);
        GLDS16(pwh + bbase3 + ko, smem + 28672 + ldsw);
        GLDS16(pwl + bbase0 + ko, smem + 32768 + ldsw);
        GLDS16(pwl + bbase1 + ko, smem + 36864 + ldsw);
        GLDS16(pwl + bbase2 + ko, smem + 40960 + ldsw);
        GLDS16(pwl + bbase3 + ko, smem + 45056 + ldsw);
        __syncthreads();

        v8h ah[4], al4[4], bh4[4], bl4[4];
        #pragma unroll
        for (int i = 0; i < 4; ++i) {
            ah[i]  = *(const v8h*)(Ah + ia[i]);
            al4[i] = *(const v8h*)(Al + ia[i]);
        }
        #pragma unroll
        for (int j = 0; j < 4; ++j) {
            bh4[j] = *(const v8h*)(Bh + ibx[j]);
            bl4[j] = *(const v8h*)(Bl + ibx[j]);
        }
        #pragma unroll
        for (int i = 0; i < 4; ++i)
            #pragma unroll
            for (int j = 0; j < 4; ++j) {
                acc[i][j] = __builtin_amdgcn_mfma_f32_16x16x32_f16(ah[i],  bh4[j], acc[i][j], 0, 0, 0);
                acc[i][j] = __builtin_amdgcn_mfma_f32_16x16x32_f16(ah[i],  bl4[j], acc[i][j], 0, 0, 0);
                acc[i][j] = __builtin_amdgcn_mfma_f32_16x16x32_f16(al4[i], bh4[j], acc[i][j], 0, 0, 0);
            }
        #pragma unroll
        for (int j = 0; j < 4; ++j) {
            bh4[j] = *(const v8h*)(Bh + ibx[j + 4]);
            bl4[j] = *(const v8h*)(Bl + ibx[j + 4]);
        }
        #pragma unroll
        for (int i = 0; i < 4; ++i)
            #pragma unroll
            for (int j = 0; j < 4; ++j) {
                acc[i][j+4] = __builtin_amdgcn_mfma_f32_16x16x32_f16(ah[i],  bh4[j], acc[i][j+4], 0, 0, 0);
                acc[i][j+4] = __builtin_amdgcn_mfma_f32_16x16x32_f16(ah[i],  bl4[j], acc[i][j+4], 0, 0, 0);
                acc[i][j+4] = __builtin_amdgcn_mfma_f32_16x16x32_f16(al4[i], bh4[j], acc[i][j+4], 0, 0, 0);
            }
    }

    // epilogue: C/D layout col=lane&15, row=(lane>>4)*4+reg  [verified m89/m91]
    float cT[8];
    #pragma unroll
    for (int j = 0; j < 8; ++j) cT[j] = colTerm[cb + wco + j * 16 + c16];
    const float de2 = (float)D_ * EPS_ * EPS_;
    #pragma unroll
    for (int i = 0; i < 4; ++i) {
        #pragma unroll
        for (int r = 0; r < 4; ++r) {
            int row_g = rb + wro + i * 16 + kq * 4 + r;
            float rt = rowTerm[row_g];
            unsigned long long best = ~0ull;
            #pragma unroll
            for (int j = 0; j < 8; ++j) {
                float sq = rt + cT[j] - 2.0f * acc[i][j][r] + de2;
                sq = fmaxf(sq, 0.0f);
                float dist = sqrtf(sq);
                unsigned long long key =
                    ((unsigned long long)__float_as_uint(dist) << 32) |
                    (unsigned int)(cb + wco + j * 16 + c16);
                best = umin64(best, key);
            }
            #pragma unroll
            for (int m = 1; m <= 8; m <<= 1) {
                unsigned long long o =
                    (unsigned long long)__shfl_xor((long long)best, m, 64);
                best = umin64(best, o);
            }
            if (c16 == 0) atomicMin(&keys[row_g], best);
        }
    }
}

// ---------- fallback fp32 path (used only if ws too small) ----------
__global__ void row_stats(const float* __restrict__ x, float* __restrict__ rowTerm) {
    int b = blockIdx.x;
    const float* xr = x + (size_t)b * D_;
    int t = threadIdx.x;
    float acc = 0.f;
    for (int i = t; i < D_; i += 256) {
        float v = xr[i];
        acc += v * v + 2.0f * EPS_ * v;
    }
    for (int off = 32; off; off >>= 1) acc += __shfl_down(acc, off, 64);
    __shared__ float s[4];
    if ((t & 63) == 0) s[t >> 6] = acc;
    __syncthreads();
    if (t == 0) rowTerm[b] = s[0] + s[1] + s[2] + s[3];
}

__global__ void col_stats(const float* __restrict__ w, float* __restrict__ colTerm) {
    int m = blockIdx.x * 256 + threadIdx.x;
    int d0 = blockIdx.y * 64;
    const float* p = w + (size_t)d0 * M_ + m;
    float acc = 0.f;
    #pragma unroll 8
    for (int d = 0; d < 64; ++d) {
        float v = p[(size_t)d * M_];
        acc += v * v - 2.0f * EPS_ * v;
    }
    atomicAdd(&colTerm[m], acc);
}

__global__ __launch_bounds__(256, 2) void som_gemm(
    const float* __restrict__ A, const float* __restrict__ Wt,
    const float* __restrict__ rowTerm, const float* __restrict__ colTerm,
    unsigned long long* __restrict__ keys)
{
    __shared__ float As[8][128];
    __shared__ float Bs[8][128];
    const int t  = threadIdx.x;
    const int rb = blockIdx.y * 128;
    const int cb = blockIdx.x * 128;
    const int tx = t & 15;
    const int ty = t >> 4;
    float acc[8][8];
    #pragma unroll
    for (int i = 0; i < 8; ++i)
        #pragma unroll
        for (int j = 0; j < 8; ++j) acc[i][j] = 0.f;
    const int la_row = t >> 1, la_k = (t & 1) * 4;
    const int lb_k = t >> 5, lb_n = (t & 31) * 4;
    const float* Aptr = A + (size_t)(rb + la_row) * D_ + la_k;
    const float* Bptr = Wt + (size_t)lb_k * M_ + cb + lb_n;
    for (int k0 = 0; k0 < D_; k0 += 8) {
        float4 av = *(const float4*)(Aptr + k0);
        float4 bv = *(const float4*)(Bptr + (size_t)k0 * M_);
        __syncthreads();
        As[la_k + 0][la_row] = av.x;
        As[la_k + 1][la_row] = av.y;
        As[la_k + 2][la_row] = av.z;
        As[la_k + 3][la_row] = av.w;
        *(float4*)&Bs[lb_k][lb_n] = bv;
        __syncthreads();
        #pragma unroll
        for (int k = 0; k < 8; ++k) {
            float a[8], b[8];
            #pragma unroll
            for (int i = 0; i < 8; ++i) a[i] = As[k][ty * 8 + i];
            #pragma unroll
            for (int j = 0; j < 8; ++j) b[j] = Bs[k][tx * 8 + j];
            #pragma unroll
            for (int i = 0; i < 8; ++i)
                #pragma unroll
                for (int j = 0; j < 8; ++j) acc[i][j] += a[i] * b[j];
        }
    }
    float rT[8], cT[8];
    #pragma unroll
    for (int i = 0; i < 8; ++i) rT[i] = rowTerm[rb + ty * 8 + i];
    #pragma unroll
    for (int j = 0; j < 8; ++j) cT[j] = colTerm[cb + tx * 8 + j];
    const float de2 = (float)D_ * EPS_ * EPS_;
    #pragma unroll
    for (int i = 0; i < 8; ++i) {
        unsigned long long best = ~0ull;
        #pragma unroll
        for (int j = 0; j < 8; ++j) {
            float sq = rT[i] + cT[j] - 2.0f * acc[i][j] + de2;
            sq = fmaxf(sq, 0.0f);
            float dist = sqrtf(sq);
            unsigned long long key =
                ((unsigned long long)__float_as_uint(dist) << 32) |
                (unsigned int)(cb + tx * 8 + j);
            best = umin64(best, key);
        }
        #pragma unroll
        for (int msk = 1; msk <= 8; msk <<= 1) {
            unsigned long long o = __shfl_xor((long long)best, msk, 64);
            best = umin64(best, (unsigned long long)o);
        }
        if (tx == 0) atomicMin(&keys[rb + ty * 8 + i], best);
    }
}

// ---------- finalize: 8 blocks of 256 rows ----------
__global__ void finalize(const unsigned long long* __restrict__ keys,
                         const float* __restrict__ loc,
                         float* __restrict__ out)
{
    int t = threadIdx.x;
    int r = blockIdx.x * 256 + t;
    unsigned long long k = keys[r];
    unsigned int idx = (unsigned int)(k & 0xFFFFFFFFu);
    float dist = __uint_as_float((unsigned int)(k >> 32));
    out[r] = (float)idx;
    out[B_ + 2 * r]     = loc[2 * idx];
    out[B_ + 2 * r + 1] = loc[2 * idx + 1];
    float sum = dist;
    for (int off = 32; off; off >>= 1) sum += __shfl_down(sum, off, 64);
    __shared__ float s[4];
    if ((t & 63) == 0) s[t >> 6] = sum;
    __syncthreads();
    if (t == 0) atomicAdd(&out[3 * B_], (s[0] + s[1] + s[2] + s[3]) / (float)B_);
}

extern "C" void kernel_launch(void* const* d_in, const int* in_sizes, int n_in,
                              void* d_out, int out_size, void* d_ws, size_t ws_size,
                              hipStream_t stream)
{
    const float* x   = (const float*)d_in[0];
    const float* w   = (const float*)d_in[1];
    const float* loc = (const float*)d_in[2];
    float* out = (float*)d_out;

    char* ws = (char*)d_ws;
    unsigned long long* keys = (unsigned long long*)ws;   // 16 KB
    float* rowTerm = (float*)(ws + (16 << 10));           //  8 KB
    float* colTerm = (float*)(ws + (24 << 10));           // 64 KB
    _Float16* xh  = (_Float16*)(ws + (1ull << 20));       //  4 MB
    _Float16* xl  = (_Float16*)(ws + (5ull << 20));       //  4 MB
    _Float16* wth = (_Float16*)(ws + (9ull << 20));       // 32 MB
    _Float16* wtl = (_Float16*)(ws + (41ull << 20));      // 32 MB
    const size_t NEED = 73ull << 20;

    if (ws_size >= NEED) {
        prep<<<321, 256, 0, stream>>>(x, w, xh, xl, wth, wtl,
                                      rowTerm, colTerm, keys, out);
        som_mfma<<<1024, 256, 0, stream>>>(
            xh, xl, wth, wtl, rowTerm, colTerm, keys);
    } else {
        hipMemsetAsync(keys, 0xFF, B_ * sizeof(unsigned long long), stream);
        hipMemsetAsync(colTerm, 0, M_ * sizeof(float), stream);
        hipMemsetAsync(out + 3 * B_, 0, sizeof(float), stream);
        row_stats<<<B_, 256, 0, stream>>>(x, rowTerm);
        col_stats<<<dim3(M_ / 256, D_ / 64), 256, 0, stream>>>(w, colTerm);
        som_gemm<<<dim3(M_ / 128, B_ / 128), 256, 0, stream>>>(
            x, w, rowTerm, colTerm, keys);
    }
    finalize<<<8, 256, 0, stream>>>(keys, loc, out);
}

// Round 2
// 299.296 us; speedup vs baseline: 1.0347x; 1.0347x over previous
//
#include <hip/hip_runtime.h>
#include <cstdint>
#include <cstddef>

// SOM BMU: dists[b,m] = ||x[b] - W[:,m] + eps||, argmin/min over m.
//   sq = rowTerm[b] + colTerm[m] - 2*dot(x[b],W[:,m]) + D*eps^2
// dot via split-precision f16 MFMA (xh.wh + xh.wl + xl.wh, ~2^-22 rel err).
// R8: 128x256 block tile (96 MFMA/wave/iter -> barrier drain amortized 8x),
// GLDS staging with PRE-SWIZZLED storage format written by the prep pass:
//   addr16(r,c) = (r>>4)*32768 + (c>>2)*1024 + (c&3)*256 + (r&15)*16
// R9: som_mfma XCD-aware swizzle (FETCH 277->122MB, time-neutral; kept).
// R10 (this round): prep occupancy fix. R9's 321-block grid = 1.25 blocks/CU;
//   65 CUs ran TWO serial blocks -> kernel ~= 2x block time, latency-bound at
//   1.3 TB/s regardless of inner structure. Now 2304 blocks (9/CU exactly):
//   W-path 2048 blocks (64 cols x 128 d, colTerm atomicAdd after LDS reduce,
//   colTerm pre-zeroed by hipMemsetAsync), x-path 256 blocks (8 rows each).
//   Uniform ~64KB/block. Target ~30us (traffic roofline 151MB -> 24us).
// Argmin via packed u64 key (dist_bits<<32 | m) + atomicMin.

#define B_  2048
#define D_  1024
#define M_  16384
#define EPS_ 1e-6f

typedef _Float16 v8h __attribute__((ext_vector_type(8)));
typedef float    v4f __attribute__((ext_vector_type(4)));

static __device__ __forceinline__ unsigned long long umin64(unsigned long long a,
                                                            unsigned long long b) {
    return a < b ? a : b;
}

// swizzled 16B-chunk address: row r, k-chunk c (8 f16 per chunk)
static __device__ __forceinline__ size_t addr16(int r, int c) {
    return (size_t)(r >> 4) * 32768 + (size_t)(c >> 2) * 1024 +
           (size_t)(c & 3) * 256 + (size_t)(r & 15) * 16;
}

#define GLDS16(g, l)                                                            \
    __builtin_amdgcn_global_load_lds(                                           \
        (const __attribute__((address_space(1))) void*)(g),                     \
        (__attribute__((address_space(3))) void*)(l), 16, 0, 0)

// ---------- fused prep ----------
// blocks 0..2047:    W-path. block = (col-group mg = blk>>3: 64 cols) x
//                    (d-chunk dc = blk&7: 128 d). One col per thread per wave,
//                    4 waves each cover 32 d. colTerm += partial (atomicAdd).
// blocks 2048..2303: x-path. 8 rows each, one row per 32-lane half-wave.
//                    x-block 0 also inits keys + loss slot.
__global__ __launch_bounds__(256) void prep(
    const float* __restrict__ x, const float* __restrict__ W,
    _Float16* __restrict__ xh, _Float16* __restrict__ xl,
    _Float16* __restrict__ wth, _Float16* __restrict__ wtl,
    float* __restrict__ rowTerm, float* __restrict__ colTerm,
    unsigned long long* __restrict__ keys, float* __restrict__ out)
{
    const int t = threadIdx.x;
    const int blk = blockIdx.x;
    if (blk < 2048) {
        __shared__ float cpart[4][64];
        const int mg = blk >> 3, dc = blk & 7;
        const int m_local = t & 63;
        const int wq = t >> 6;
        const int m = mg * 64 + m_local;
        const float* wp = W + m;
        float part = 0.f;
        #pragma unroll
        for (int cl = 0; cl < 4; ++cl) {
            const int c = dc * 16 + wq * 4 + cl;     // k-chunk (8 d each)
            const int d0 = c * 8;
            float vv[8];
            #pragma unroll
            for (int e = 0; e < 8; ++e)
                vv[e] = wp[(size_t)(d0 + e) * M_];   // wave = 256B coalesced
            v8h h, l;
            #pragma unroll
            for (int e = 0; e < 8; ++e) {
                _Float16 hi = (_Float16)vv[e];
                h[e] = hi; l[e] = (_Float16)(vv[e] - (float)hi);
                part += vv[e] * vv[e] - 2.0f * EPS_ * vv[e];
            }
            const size_t a = addr16(m, c);
            *(v8h*)((char*)wth + a) = h;             // lanes 0-15: 256B contig
            *(v8h*)((char*)wtl + a) = l;
        }
        cpart[wq][m_local] = part;
        __syncthreads();
        if (t < 64)
            atomicAdd(&colTerm[mg * 64 + t],
                      cpart[0][t] + cpart[1][t] + cpart[2][t] + cpart[3][t]);
    } else {
        const int xb = blk - 2048;
        const int w = t >> 6, L = t & 63;
        const int hl = L & 31;
        const int r = xb * 8 + 2 * w + (L >> 5);
        const float* xr = x + (size_t)r * D_;
        float part = 0.f;
        #pragma unroll
        for (int i = 0; i < 4; ++i) {
            const int c = 32 * i + hl;               // half-wave = 1KB coalesced
            float4 q1 = *(const float4*)(xr + 8 * c);
            float4 q2 = *(const float4*)(xr + 8 * c + 4);
            float vv[8] = {q1.x, q1.y, q1.z, q1.w, q2.x, q2.y, q2.z, q2.w};
            v8h h, l;
            #pragma unroll
            for (int e = 0; e < 8; ++e) {
                _Float16 hi = (_Float16)vv[e];
                h[e] = hi; l[e] = (_Float16)(vv[e] - (float)hi);
                part += vv[e] * vv[e] + 2.0f * EPS_ * vv[e];
            }
            const size_t a = addr16(r, c);
            *(v8h*)((char*)xh + a) = h;
            *(v8h*)((char*)xl + a) = l;
        }
        #pragma unroll
        for (int msk = 1; msk <= 16; msk <<= 1)
            part += __shfl_xor(part, msk, 64);       // stays within 32-lane half
        if (hl == 0) rowTerm[r] = part;
        if (xb == 0) {
            for (int i = t; i < B_; i += 256) keys[i] = ~0ull;
            if (t == 0) out[3 * B_] = 0.f;
        }
    }
}

// ---------- main MFMA distance GEMM + argmin ----------
// 128x256 block tile, 4 waves (2x2, each 64 rows x 128 cols), BK=32.
__global__ __launch_bounds__(256, 2) void som_mfma(
    const _Float16* __restrict__ xh, const _Float16* __restrict__ xl,
    const _Float16* __restrict__ wth, const _Float16* __restrict__ wtl,
    const float* __restrict__ rowTerm, const float* __restrict__ colTerm,
    unsigned long long* __restrict__ keys)
{
    __shared__ __align__(16) char smem[49152];   // Ah 8K | Al 8K | Bh 16K | Bl 16K
    _Float16* Ah = (_Float16*)smem;
    _Float16* Al = (_Float16*)(smem + 8192);
    _Float16* Bh = (_Float16*)(smem + 16384);
    _Float16* Bl = (_Float16*)(smem + 32768);

    const int t = threadIdx.x;
    const int g = blockIdx.x;
    // XCD-aware: round-robin dispatch puts g on XCD g&7; all 16 row-blocks of
    // a slab share g&7 -> same XCD L2 -> W slab fetched once per XCD.
    // bijective: g = (slab&7) + 8*row + 128*(slab>>3)
    const int slab = (g & 7) + 8 * (g >> 7);
    const int cb = slab * 256;
    const int rb = ((g >> 3) & 15) * 128;
    const int L = t & 63, w = t >> 6;
    const int wro = (w >> 1) * 64;
    const int wco = (w & 1) * 128;
    const int c16 = L & 15, kq = L >> 4;

    // staging: per call, wave wgrp covers one 16-row group (1 KB linear)
    const int wgrp = t >> 6;
    const int lane16 = (t & 63) * 16;
    const int ldsw = wgrp * 1024;                 // wave-uniform LDS base
    const size_t abase0 = (size_t)((rb >> 4) + wgrp) * 32768 + lane16;
    const size_t abase1 = abase0 + 4ull * 32768;
    const size_t bbase0 = (size_t)((cb >> 4) + wgrp) * 32768 + lane16;
    const size_t bbase1 = bbase0 + 4ull * 32768;
    const size_t bbase2 = bbase0 + 8ull * 32768;
    const size_t bbase3 = bbase0 + 12ull * 32768;

    const char* pxh = (const char*)xh;
    const char* pxl = (const char*)xl;
    const char* pwh = (const char*)wth;
    const char* pwl = (const char*)wtl;

    v4f acc[4][8];
    #pragma unroll
    for (int i = 0; i < 4; ++i)
        #pragma unroll
        for (int j = 0; j < 8; ++j) acc[i][j] = (v4f){0.f, 0.f, 0.f, 0.f};

    // fragment read offsets (f16 units): group grp -> grp*512 + lofs
    // lofs: chunk (L>>4)*128 + row (L&15)*8 -> 16-lane groups on 16
    // consecutive slots (conflict-free)
    const int lofs = kq * 128 + c16 * 8;
    int ia[4], ibx[8];
    #pragma unroll
    for (int i = 0; i < 4; ++i) ia[i] = ((wro >> 4) + i) * 512 + lofs;
    #pragma unroll
    for (int j = 0; j < 8; ++j) ibx[j] = ((wco >> 4) + j) * 512 + lofs;

    for (int S = 0; S < 32; ++S) {
        const size_t ko = (size_t)S * 1024;
        __syncthreads();
        GLDS16(pxh + abase0 + ko, smem + ldsw);
        GLDS16(pxh + abase1 + ko, smem + 4096 + ldsw);
        GLDS16(pxl + abase0 + ko, smem + 8192 + ldsw);
        GLDS16(pxl + abase1 + ko, smem + 12288 + ldsw);
        GLDS16(pwh + bbase0 + ko, smem + 16384 + ldsw);
        GLDS16(pwh + bbase1 + ko, smem + 20480 + ldsw);
        GLDS16(pwh + bbase2 + ko, smem + 24576 + ldsw);
        GLDS16(pwh + bbase3 + ko, smem + 28672 + ldsw);
        GLDS16(pwl + bbase0 + ko, smem + 32768 + ldsw);
        GLDS16(pwl + bbase1 + ko, smem + 36864 + ldsw);
        GLDS16(pwl + bbase2 + ko, smem + 40960 + ldsw);
        GLDS16(pwl + bbase3 + ko, smem + 45056 + ldsw);
        __syncthreads();

        v8h ah[4], al4[4], bh4[4], bl4[4];
        #pragma unroll
        for (int i = 0; i < 4; ++i) {
            ah[i]  = *(const v8h*)(Ah + ia[i]);
            al4[i] = *(const v8h*)(Al + ia[i]);
        }
        #pragma unroll
        for (int j = 0; j < 4; ++j) {
            bh4[j] = *(const v8h*)(Bh + ibx[j]);
            bl4[j] = *(const v8h*)(Bl + ibx[j]);
        }
        #pragma unroll
        for (int i = 0; i < 4; ++i)
            #pragma unroll
            for (int j = 0; j < 4; ++j) {
                acc[i][j] = __builtin_amdgcn_mfma_f32_16x16x32_f16(ah[i],  bh4[j], acc[i][j], 0, 0, 0);
                acc[i][j] = __builtin_amdgcn_mfma_f32_16x16x32_f16(ah[i],  bl4[j], acc[i][j], 0, 0, 0);
                acc[i][j] = __builtin_amdgcn_mfma_f32_16x16x32_f16(al4[i], bh4[j], acc[i][j], 0, 0, 0);
            }
        #pragma unroll
        for (int j = 0; j < 4; ++j) {
            bh4[j] = *(const v8h*)(Bh + ibx[j + 4]);
            bl4[j] = *(const v8h*)(Bl + ibx[j + 4]);
        }
        #pragma unroll
        for (int i = 0; i < 4; ++i)
            #pragma unroll
            for (int j = 0; j < 4; ++j) {
                acc[i][j+4] = __builtin_amdgcn_mfma_f32_16x16x32_f16(ah[i],  bh4[j], acc[i][j+4], 0, 0, 0);
                acc[i][j+4] = __builtin_amdgcn_mfma_f32_16x16x32_f16(ah[i],  bl4[j], acc[i][j+4], 0, 0, 0);
                acc[i][j+4] = __builtin_amdgcn_mfma_f32_16x16x32_f16(al4[i], bh4[j], acc[i][j+4], 0, 0, 0);
            }
    }

    // epilogue: C/D layout col=lane&15, row=(lane>>4)*4+reg  [verified m89/m91]
    float cT[8];
    #pragma unroll
    for (int j = 0; j < 8; ++j) cT[j] = colTerm[cb + wco + j * 16 + c16];
    const float de2 = (float)D_ * EPS_ * EPS_;
    #pragma unroll
    for (int i = 0; i < 4; ++i) {
        #pragma unroll
        for (int r = 0; r < 4; ++r) {
            int row_g = rb + wro + i * 16 + kq * 4 + r;
            float rt = rowTerm[row_g];
            unsigned long long best = ~0ull;
            #pragma unroll
            for (int j = 0; j < 8; ++j) {
                float sq = rt + cT[j] - 2.0f * acc[i][j][r] + de2;
                sq = fmaxf(sq, 0.0f);
                float dist = sqrtf(sq);
                unsigned long long key =
                    ((unsigned long long)__float_as_uint(dist) << 32) |
                    (unsigned int)(cb + wco + j * 16 + c16);
                best = umin64(best, key);
            }
            #pragma unroll
            for (int m = 1; m <= 8; m <<= 1) {
                unsigned long long o =
                    (unsigned long long)__shfl_xor((long long)best, m, 64);
                best = umin64(best, o);
            }
            if (c16 == 0) atomicMin(&keys[row_g], best);
        }
    }
}

// ---------- fallback fp32 path (used only if ws too small) ----------
__global__ void row_stats(const float* __restrict__ x, float* __restrict__ rowTerm) {
    int b = blockIdx.x;
    const float* xr = x + (size_t)b * D_;
    int t = threadIdx.x;
    float acc = 0.f;
    for (int i = t; i < D_; i += 256) {
        float v = xr[i];
        acc += v * v + 2.0f * EPS_ * v;
    }
    for (int off = 32; off; off >>= 1) acc += __shfl_down(acc, off, 64);
    __shared__ float s[4];
    if ((t & 63) == 0) s[t >> 6] = acc;
    __syncthreads();
    if (t == 0) rowTerm[b] = s[0] + s[1] + s[2] + s[3];
}

__global__ void col_stats(const float* __restrict__ w, float* __restrict__ colTerm) {
    int m = blockIdx.x * 256 + threadIdx.x;
    int d0 = blockIdx.y * 64;
    const float* p = w + (size_t)d0 * M_ + m;
    float acc = 0.f;
    #pragma unroll 8
    for (int d = 0; d < 64; ++d) {
        float v = p[(size_t)d * M_];
        acc += v * v - 2.0f * EPS_ * v;
    }
    atomicAdd(&colTerm[m], acc);
}

__global__ __launch_bounds__(256, 2) void som_gemm(
    const float* __restrict__ A, const float* __restrict__ Wt,
    const float* __restrict__ rowTerm, const float* __restrict__ colTerm,
    unsigned long long* __restrict__ keys)
{
    __shared__ float As[8][128];
    __shared__ float Bs[8][128];
    const int t  = threadIdx.x;
    const int rb = blockIdx.y * 128;
    const int cb = blockIdx.x * 128;
    const int tx = t & 15;
    const int ty = t >> 4;
    float acc[8][8];
    #pragma unroll
    for (int i = 0; i < 8; ++i)
        #pragma unroll
        for (int j = 0; j < 8; ++j) acc[i][j] = 0.f;
    const int la_row = t >> 1, la_k = (t & 1) * 4;
    const int lb_k = t >> 5, lb_n = (t & 31) * 4;
    const float* Aptr = A + (size_t)(rb + la_row) * D_ + la_k;
    const float* Bptr = Wt + (size_t)lb_k * M_ + cb + lb_n;
    for (int k0 = 0; k0 < D_; k0 += 8) {
        float4 av = *(const float4*)(Aptr + k0);
        float4 bv = *(const float4*)(Bptr + (size_t)k0 * M_);
        __syncthreads();
        As[la_k + 0][la_row] = av.x;
        As[la_k + 1][la_row] = av.y;
        As[la_k + 2][la_row] = av.z;
        As[la_k + 3][la_row] = av.w;
        *(float4*)&Bs[lb_k][lb_n] = bv;
        __syncthreads();
        #pragma unroll
        for (int k = 0; k < 8; ++k) {
            float a[8], b[8];
            #pragma unroll
            for (int i = 0; i < 8; ++i) a[i] = As[k][ty * 8 + i];
            #pragma unroll
            for (int j = 0; j < 8; ++j) b[j] = Bs[k][tx * 8 + j];
            #pragma unroll
            for (int i = 0; i < 8; ++i)
                #pragma unroll
                for (int j = 0; j < 8; ++j) acc[i][j] += a[i] * b[j];
        }
    }
    float rT[8], cT[8];
    #pragma unroll
    for (int i = 0; i < 8; ++i) rT[i] = rowTerm[rb + ty * 8 + i];
    #pragma unroll
    for (int j = 0; j < 8; ++j) cT[j] = colTerm[cb + tx * 8 + j];
    const float de2 = (float)D_ * EPS_ * EPS_;
    #pragma unroll
    for (int i = 0; i < 8; ++i) {
        unsigned long long best = ~0ull;
        #pragma unroll
        for (int j = 0; j < 8; ++j) {
            float sq = rT[i] + cT[j] - 2.0f * acc[i][j] + de2;
            sq = fmaxf(sq, 0.0f);
            float dist = sqrtf(sq);
            unsigned long long key =
                ((unsigned long long)__float_as_uint(dist) << 32) |
                (unsigned int)(cb + tx * 8 + j);
            best = umin64(best, key);
        }
        #pragma unroll
        for (int msk = 1; msk <= 8; msk <<= 1) {
            unsigned long long o = __shfl_xor((long long)best, msk, 64);
            best = umin64(best, (unsigned long long)o);
        }
        if (tx == 0) atomicMin(&keys[rb + ty * 8 + i], best);
    }
}

// ---------- finalize: 8 blocks of 256 rows ----------
__global__ void finalize(const unsigned long long* __restrict__ keys,
                         const float* __restrict__ loc,
                         float* __restrict__ out)
{
    int t = threadIdx.x;
    int r = blockIdx.x * 256 + t;
    unsigned long long k = keys[r];
    unsigned int idx = (unsigned int)(k & 0xFFFFFFFFu);
    float dist = __uint_as_float((unsigned int)(k >> 32));
    out[r] = (float)idx;
    out[B_ + 2 * r]     = loc[2 * idx];
    out[B_ + 2 * r + 1] = loc[2 * idx + 1];
    float sum = dist;
    for (int off = 32; off; off >>= 1) sum += __shfl_down(sum, off, 64);
    __shared__ float s[4];
    if ((t & 63) == 0) s[t >> 6] = sum;
    __syncthreads();
    if (t == 0) atomicAdd(&out[3 * B_], (s[0] + s[1] + s[2] + s[3]) / (float)B_);
}

extern "C" void kernel_launch(void* const* d_in, const int* in_sizes, int n_in,
                              void* d_out, int out_size, void* d_ws, size_t ws_size,
                              hipStream_t stream)
{
    const float* x   = (const float*)d_in[0];
    const float* w   = (const float*)d_in[1];
    const float* loc = (const float*)d_in[2];
    float* out = (float*)d_out;

    char* ws = (char*)d_ws;
    unsigned long long* keys = (unsigned long long*)ws;   // 16 KB
    float* rowTerm = (float*)(ws + (16 << 10));           //  8 KB
    float* colTerm = (float*)(ws + (24 << 10));           // 64 KB
    _Float16* xh  = (_Float16*)(ws + (1ull << 20));       //  4 MB
    _Float16* xl  = (_Float16*)(ws + (5ull << 20));       //  4 MB
    _Float16* wth = (_Float16*)(ws + (9ull << 20));       // 32 MB
    _Float16* wtl = (_Float16*)(ws + (41ull << 20));      // 32 MB
    const size_t NEED = 73ull << 20;

    if (ws_size >= NEED) {
        hipMemsetAsync(colTerm, 0, M_ * sizeof(float), stream);
        prep<<<2304, 256, 0, stream>>>(x, w, xh, xl, wth, wtl,
                                       rowTerm, colTerm, keys, out);
        som_mfma<<<1024, 256, 0, stream>>>(
            xh, xl, wth, wtl, rowTerm, colTerm, keys);
    } else {
        hipMemsetAsync(keys, 0xFF, B_ * sizeof(unsigned long long), stream);
        hipMemsetAsync(colTerm, 0, M_ * sizeof(float), stream);
        hipMemsetAsync(out + 3 * B_, 0, sizeof(float), stream);
        row_stats<<<B_, 256, 0, stream>>>(x, rowTerm);
        col_stats<<<dim3(M_ / 256, D_ / 64), 256, 0, stream>>>(w, colTerm);
        som_gemm<<<dim3(M_ / 128, B_ / 128), 256, 0, stream>>>(
            x, w, rowTerm, colTerm, keys);
    }
    finalize<<<8, 256, 0, stream>>>(keys, loc, out);
}